// Round 7
// baseline (225.302 us; speedup 1.0000x reference)
//
#include <hip/hip_runtime.h>

// DynamicFilter: out[b,c,h,w] = sum_p (y[c*9+p] + bias[c*9+p]) * x[b,c,h+dh,w+dw]
//   y[o] = sum_c' x[b,c',h,w] * W[o,c']   (GEMM M=65536, N=2304, K=256, bf16 MFMA)
// B=4, C=256, H=W=128, 9 taps.
// R6 150us (ring-3, counted vmcnt). R9 150us (8-wave, ring-4, dedicated Y):
//   schedule changes flat -> throughput-bound on LDS pipe. Evidence:
//   SQ_LDS_BANK_CONFLICT = 1.416e7 constant across R4..R9 (through two Y
//   rewrites) = +6 cy on each of the 2.36M B ds_read_b128 (row pitch 256 B
//   kills lrow's bank contribution; 8 lanes per 4-bank group at 8 rows).
// R10: instruction-ordered Wb layout. wconv pre-permutes so each MFMA's 64
//   lane-fragments are contiguous: read = uniform base + lane*16 (m134
//   conflict-free pattern). XOR swizzle deleted; ds_read offsets become
//   immediates. R9 sync skeleton byte-for-byte identical.
// Wb bijection: for out o, k: chunk=o/144, oo=o%144, ni=oo/16, lrow=oo%16;
//   kh=k/128, s=(k%128)/32, q=(k%32)/8, e=k%8; j=kh*3+ni/3; ni_=ni%3;
//   addr = chunk*73728 + j*12288 + (s*3+ni_)*1024 + (q*16+lrow)*16 + e*2.

typedef __attribute__((ext_vector_type(8))) short bf16x8;   // 8 bf16 = 4 VGPRs
typedef __attribute__((ext_vector_type(4))) float f32x4;    // MFMA 16x16 acc

__device__ __forceinline__ unsigned int f2bf(float f) {
    unsigned int u = __float_as_uint(f);
    return (u + 0x7fffu + ((u >> 16) & 1u)) >> 16;   // RNE
}
__device__ __forceinline__ unsigned int pack2(float a, float b) {
    return f2bf(a) | (f2bf(b) << 16);
}

// ---------------------------------------------------------------------------
// Kernel 1: W (2304x256 fp32) -> Wb bf16, instruction-ordered (see header).
// Thread idx -> out o = idx>>5, 8-k group g = idx&31 (k = g*8..g*8+7).
// ---------------------------------------------------------------------------
__global__ __launch_bounds__(256) void wconv_kernel(const float* __restrict__ W,
                                                    unsigned char* __restrict__ Wb) {
    int idx = blockIdx.x * 256 + threadIdx.x;    // 73728 = 2304 * 32 groups
    int o = idx >> 5, g = idx & 31;
    const float4* src = (const float4*)(W + ((size_t)o << 8) + ((size_t)g << 3));
    float4 v0 = src[0], v1 = src[1];
    uint4 pk;
    pk.x = pack2(v0.x, v0.y); pk.y = pack2(v0.z, v0.w);
    pk.z = pack2(v1.x, v1.y); pk.w = pack2(v1.z, v1.w);
    int kh = g >> 4, g2 = g & 15, s = g2 >> 2, q = g2 & 3;
    int chunk = o / 144, oo = o - chunk * 144;
    int ni = oo >> 4, lrow = oo & 15;
    int j = kh * 3 + ni / 3, ni_ = ni % 3;
    size_t dst = (size_t)chunk * 73728 + (size_t)j * 12288
               + (size_t)(s * 3 + ni_) * 1024 + (size_t)((q << 4) + lrow) * 16;
    *(uint4*)(Wb + dst) = pk;
}

// ---------------------------------------------------------------------------
// Kernel 2. LDS map: ring bufs 0..3 at 0/12288/24576/36864; per-wave Y
// (9216 B, pitch 16 dwords, XOR-swizzled) at 49152 + wv*9216. Total 122880.
// Sub-tile j (0..5): kh = j/3, ni-block = j%3, ring buf = j%4.
// ---------------------------------------------------------------------------

// Drain-barrier: wave's LDS ops complete before the HW barrier; vmcnt counted
// (N in flight allowed). Single asm blob = compiler memory fence, no seams.
#define SYNC_VM(N) asm volatile("s_waitcnt vmcnt(" #N ") lgkmcnt(0)\n\ts_barrier" ::: "memory")
#define SYNC_LG    asm volatile("s_waitcnt lgkmcnt(0)\n\ts_barrier" ::: "memory")
#define WAIT_LGKM0 asm volatile("s_waitcnt lgkmcnt(0)" ::: "memory")
#define FENCE      asm volatile("" ::: "memory")   // compile-time order pin only

// Stage sub-tile J of chunk CH into ring buf J%4. Slices of 2048 B; wave wv
// stages slice wv%6 with 2 x global_load_lds(16B); waves 6,7 duplicate
// slices 0,1 (identical bytes). Per-wave vmcnt += 2, uniform across waves.
#define STAGE(CH, J)                                                            \
    do {                                                                        \
        const int sl_ = (wv < 6) ? wv : (wv - 6);                               \
        const unsigned char* bs_ = Wb + (size_t)(CH) * 73728                    \
            + (size_t)(J) * 12288 + sl_ * 2048 + (lane << 4);                   \
        unsigned char* bd_ = smem + ((J) % 4) * 12288 + sl_ * 2048;             \
        __builtin_amdgcn_global_load_lds(                                       \
            (const __attribute__((address_space(1))) void*)(bs_),               \
            (__attribute__((address_space(3))) void*)(bd_), 16, 0, 0);          \
        __builtin_amdgcn_global_load_lds(                                       \
            (const __attribute__((address_space(1))) void*)(bs_ + 1024),        \
            (__attribute__((address_space(3))) void*)(bd_ + 1024), 16, 0, 0);   \
    } while (0)

// 24 MFMAs on sub-tile J (3 ni x 2 mi x 4 s): 6 independent acc chains per s.
// B read: uniform base + lane*16 (conflict-free, m134 pattern); the
// (s*3+ni)*1024 term folds into the ds_read_b128 offset immediate.
#define MFMA_SUB(J)                                                             \
    do {                                                                        \
        const int kh_ = (J) / 3, snib_ = ((J) % 3) * 3;                         \
        const unsigned char* bb_ = smem + ((J) % 4) * 12288 + (lane << 4);      \
        _Pragma("unroll")                                                       \
        for (int s_ = 0; s_ < 4; ++s_) {                                        \
            const bf16x8 a0_ = afr[(kh_ << 2) + s_];                            \
            const bf16x8 a1_ = afr[8 + (kh_ << 2) + s_];                        \
            _Pragma("unroll")                                                   \
            for (int ni_ = 0; ni_ < 3; ++ni_) {                                 \
                const bf16x8 bq_ = *(const bf16x8*)(bb_ + ((s_ * 3 + ni_) << 10)); \
                acc[0][snib_ + ni_] = __builtin_amdgcn_mfma_f32_16x16x32_bf16(  \
                    a0_, bq_, acc[0][snib_ + ni_], 0, 0, 0);                    \
                acc[1][snib_ + ni_] = __builtin_amdgcn_mfma_f32_16x16x32_bf16(  \
                    a1_, bq_, acc[1][snib_ + ni_], 0, 0, 0);                    \
            }                                                                   \
        }                                                                       \
    } while (0)

__global__ __launch_bounds__(512, 2) void dfgemm_kernel(
        const unsigned char* __restrict__ Wb, const float* __restrict__ x,
        const float* __restrict__ bias, float* __restrict__ out) {
    __shared__ __align__(16) unsigned char smem[122880];

    const int t = threadIdx.x;
    const int lane = t & 63, wv = t >> 6;        // wv 0..7
    const int quad = lane >> 4, lrow = lane & 15;

    const int b = blockIdx.x >> 6;               // image 0..3
    const int hp = blockIdx.x & 63;              // row pair
    const int h = (hp << 1) + (wv >> 2);         // this wave's row
    const int wq = wv & 3;                       // px quarter within the row

    // Warm the pipeline: chunk 0 subs 0..3 in flight while afr loads run.
    STAGE(0, 0); STAGE(0, 1); STAGE(0, 2); STAGE(0, 3);

    // ---- A fragments direct from x: afr[mi*8+gg][j] = bf16(x[b, gg*32+quad*8+j, h, w]) ----
    bf16x8 afr[16];
    {
        const float* xrow = x + ((size_t)b << 22) + (h << 7);
        #pragma unroll
        for (int mi = 0; mi < 2; ++mi) {
            const int w = (wq << 5) + (mi << 4) + lrow;
            #pragma unroll
            for (int gg = 0; gg < 8; ++gg) {
                const float* p = xrow + ((size_t)((gg << 5) + (quad << 3)) << 14) + w;
                float v[8];
                #pragma unroll
                for (int e = 0; e < 8; ++e) v[e] = p[(size_t)e << 14];
                uint4 pk;
                pk.x = pack2(v[0], v[1]); pk.y = pack2(v[2], v[3]);
                pk.z = pack2(v[4], v[5]); pk.w = pack2(v[6], v[7]);
                afr[(mi << 3) + gg] = *(const bf16x8*)&pk;
            }
        }
    }
    SYNC_VM(0);                        // prologue only: subs 0-3 landed, full drain

    #pragma unroll 1
    for (int chunk = 0; chunk < 16; ++chunk) {
        const int c1 = (chunk + 1) & 15;         // tail wraps: harmless re-stage
        f32x4 acc[2][9];
        const f32x4 zero = {0.f, 0.f, 0.f, 0.f};
        #pragma unroll
        for (int mi = 0; mi < 2; ++mi)
            #pragma unroll
            for (int ni = 0; ni < 9; ++ni) acc[mi][ni] = zero;

        // ph0: sub0 (staged ph5 prev) force-retired by the epilogue's
        // consumed patch loads; VM(8) only bounds the <=8 out-stores.
        SYNC_VM(8);
        MFMA_SUB(0);

        SYNC_VM(8);                            // ph1: sub1 (pre-epi, FENCEd) retired
        STAGE(chunk, 4);                       // buf0 (sub0 readers drained)
        MFMA_SUB(1);

        SYNC_VM(8);                            // ph2: sub2 (ph3 prev) retired
        STAGE(chunk, 5);                       // buf1
        MFMA_SUB(2);

        SYNC_VM(8);                            // ph3: sub3 (ph4 prev) retired
        STAGE(c1, 2);                          // buf2
        MFMA_SUB(3);

        SYNC_VM(4);                            // ph4: retire sub4 (ph1); keep ph2+ph3
        STAGE(c1, 3);                          // buf3
        MFMA_SUB(4);

        SYNC_VM(4);                            // ph5: retire sub5 (ph2); keep ph3+ph4
        STAGE(c1, 0);                          // buf0 (sub4 readers drained)
        MFMA_SUB(5);

        SYNC_LG;                               // all M5 buf1 reads drained
        STAGE(c1, 1);                          // buf1; lands during epilogue
        FENCE;                                 // pin stage BEFORE patch loads/stores

        // ---- epilogue: per-wave Y [144 out][16-dword pitch, XOR-swizzled],
        //      dedicated region -> no barriers, no vm drains ----
        float* Y = (float*)(smem + 49152 + wv * 9216);
        #pragma unroll
        for (int half = 0; half < 2; ++half) {
            #pragma unroll
            for (int ni = 0; ni < 9; ++ni) {
                const int o = (ni << 4) + lrow;          // o&3 == lrow&3
                *(f32x4*)(Y + (o << 4) + ((quad ^ (lrow & 3)) << 2)) = acc[half][ni];
            }
            WAIT_LGKM0;                        // wave-local LDS RAW

            const int w = (wq << 5) + (half << 4) + lrow;    // this lane's pixel
            #pragma unroll
            for (int it = 0; it < 4; ++it) {
                const int cgl = (it << 2) + quad;            // 0..15
                const int cg = (chunk << 4) + cgl;           // channel 0..255
                const int ob = cgl * 9;                      // first out row
                const float* bp = bias + cg * 9;
                const float* xc = x + ((size_t)((b << 8) + cg) << 14);
                float sum = 0.f;
                #pragma unroll
                for (int p = 0; p < 9; ++p) {
                    const int o = ob + p;
                    const float yv = Y[(o << 4) + (lrow ^ ((o & 3) << 2))];
                    const int hh = h + p / 3 - 1, ww = w + p % 3 - 1;
                    float xv = 0.f;
                    if ((unsigned)hh < 128u && (unsigned)ww < 128u)
                        xv = xc[(hh << 7) + ww];             // fp32 patch
                    sum += (yv + bp[p]) * xv;
                }
                out[((size_t)((b << 8) + cg) << 14) + (h << 7) + w] = sum;
            }
        }
    }
}

extern "C" void kernel_launch(void* const* d_in, const int* in_sizes, int n_in,
                              void* d_out, int out_size, void* d_ws, size_t ws_size,
                              hipStream_t stream) {
    const float* x    = (const float*)d_in[0];   // 4*256*128*128
    const float* W    = (const float*)d_in[1];   // 2304*256
    const float* bias = (const float*)d_in[2];   // 2304
    float* out = (float*)d_out;

    unsigned char* Wb = (unsigned char*)d_ws;    // 1,179,648 B

    wconv_kernel<<<288, 256, 0, stream>>>(W, Wb);
    dfgemm_kernel<<<256, 512, 0, stream>>>(Wb, x, bias, out);
}

// Round 9
// 213.846 us; speedup vs baseline: 1.0536x; 1.0536x over previous
//
#include <hip/hip_runtime.h>

// DynamicFilter: out[b,c,h,w] = sum_p (y[c*9+p] + bias[c*9+p]) * x[b,c,h+dh,w+dw]
//   y[o] = sum_c' x[b,c',h,w] * W[o,c']   (GEMM M=65536, N=2304, K=256, bf16 MFMA)
// B=4, C=256, H=W=128, 9 taps.
// R6/R9 150us (schedule changes flat). R10: conflict-free B reads (1.4e7 ->
//   4.7e6) ALSO flat -> LDS conflicts were hidden; remaining serial block is
//   the epilogue Y transpose (LDS write->lgkm->read round trip, ~33us/CU).
// R11: delete the transpose. (a) Swap MFMA operands: mfma(Wb, afr, acc) ->
//   acc = C[out_reg][px_lane]; lane&15 = pixel, rows = outs. A/B fragment
//   layouts are identical (lane&15=row/col, lane>>4=k-group) so both existing
//   fragments work as-is. (b) Channel-aligned out-permutation folded into
//   Wb (wconv): D-slot (ni, quad, j) holds channel c=quad*4+(ni*4+j)/9, tap
//   p=(ni*4+j)%9 -> each lane owns 4 WHOLE channels x 9 taps in acc with
//   compile-time indices (idx=c4*9+p; ni=idx/4; j=idx%4). Epilogue = pure
//   reg FMA + patch loads + 8 stores. Zero LDS ops, Y region deleted
//   (LDS 122880 -> 49152). Sync skeleton + vmcnt counts byte-identical to
//   R9/R10 (stage = +2 vm/wave; epilogue's consumed bias/patch loads still
//   force-retire prefetched subs; <=8 stores outstanding at loop top).
// (R8 bench slot was an infra failure - container died twice; this is R11
//  resubmitted unchanged after a full correctness re-audit.)

typedef __attribute__((ext_vector_type(8))) short bf16x8;   // 8 bf16 = 4 VGPRs
typedef __attribute__((ext_vector_type(4))) float f32x4;    // MFMA 16x16 acc

__device__ __forceinline__ unsigned int f2bf(float f) {
    unsigned int u = __float_as_uint(f);
    return (u + 0x7fffu + ((u >> 16) & 1u)) >> 16;   // RNE
}
__device__ __forceinline__ unsigned int pack2(float a, float b) {
    return f2bf(a) | (f2bf(b) << 16);
}

// ---------------------------------------------------------------------------
// Kernel 1: W (2304x256 fp32) -> Wb bf16, instruction-ordered A-fragments
// with channel-aligned out permutation:
//   o: chunk=o/144, oc=o%144, c_local=oc/9, p=oc%9
//   q=c_local/4, c4=c_local%4, idx=c4*9+p, ni=idx/4, j=idx%4, r=q*4+j
//   k: kh=k/128, s=(k%128)/32, kq=(k%32)/8, e=k%8; jsub=kh*3+ni/3; ni_=ni%3
//   dst = chunk*73728 + jsub*12288 + (s*3+ni_)*1024 + (kq*16+r)*16 + e*2
// ---------------------------------------------------------------------------
__global__ __launch_bounds__(256) void wconv_kernel(const float* __restrict__ W,
                                                    unsigned char* __restrict__ Wb) {
    int idx0 = blockIdx.x * 256 + threadIdx.x;   // 73728 = 2304 * 32 groups
    int o = idx0 >> 5, g = idx0 & 31;
    const float4* src = (const float4*)(W + ((size_t)o << 8) + ((size_t)g << 3));
    float4 v0 = src[0], v1 = src[1];
    uint4 pk;
    pk.x = pack2(v0.x, v0.y); pk.y = pack2(v0.z, v0.w);
    pk.z = pack2(v1.x, v1.y); pk.w = pack2(v1.z, v1.w);
    int kh = g >> 4, g2 = g & 15, s = g2 >> 2, kq = g2 & 3;
    int chunk = o / 144, oc = o - chunk * 144;
    int c_local = oc / 9, p = oc - c_local * 9;
    int q = c_local >> 2, c4 = c_local & 3;
    int idx = c4 * 9 + p;
    int ni = idx >> 2, j = idx & 3, r = (q << 2) + j;
    int jsub = kh * 3 + ni / 3, ni_ = ni % 3;
    size_t dst = (size_t)chunk * 73728 + (size_t)jsub * 12288
               + (size_t)(s * 3 + ni_) * 1024 + (size_t)((kq << 4) + r) * 16;
    *(uint4*)(Wb + dst) = pk;
}

// ---------------------------------------------------------------------------
// Kernel 2. LDS map: ring bufs 0..3 at 0/12288/24576/36864 only. 49152 B.
// Sub-tile j (0..5): kh = j/3, ni-block = j%3, ring buf = j%4.
// Phase/WAR structure identical to R9/R10 (see chains in R9 header).
// ---------------------------------------------------------------------------

#define SYNC_VM(N) asm volatile("s_waitcnt vmcnt(" #N ") lgkmcnt(0)\n\ts_barrier" ::: "memory")
#define SYNC_LG    asm volatile("s_waitcnt lgkmcnt(0)\n\ts_barrier" ::: "memory")
#define FENCE      asm volatile("" ::: "memory")   // compile-time order pin only

// Stage sub-tile J of chunk CH into ring buf J%4. Slices of 2048 B; wave wv
// stages slice wv%6 with 2 x global_load_lds(16B); waves 6,7 duplicate
// slices 0,1 (identical bytes). Per-wave vmcnt += 2, uniform across waves.
#define STAGE(CH, J)                                                            \
    do {                                                                        \
        const int sl_ = (wv < 6) ? wv : (wv - 6);                               \
        const unsigned char* bs_ = Wb + (size_t)(CH) * 73728                    \
            + (size_t)(J) * 12288 + sl_ * 2048 + (lane << 4);                   \
        unsigned char* bd_ = smem + ((J) % 4) * 12288 + sl_ * 2048;             \
        __builtin_amdgcn_global_load_lds(                                       \
            (const __attribute__((address_space(1))) void*)(bs_),               \
            (__attribute__((address_space(3))) void*)(bd_), 16, 0, 0);          \
        __builtin_amdgcn_global_load_lds(                                       \
            (const __attribute__((address_space(1))) void*)(bs_ + 1024),        \
            (__attribute__((address_space(3))) void*)(bd_ + 1024), 16, 0, 0);   \
    } while (0)

// 24 MFMAs on sub-tile J (3 ni x 2 mi x 4 s). OPERANDS SWAPPED vs R10:
// A = Wb fragment (uniform base + lane*16, conflict-free), B = afr.
// acc[mi][ni] = C[out_row][px_col]: col=lane&15=px, row=quad*4+reg=out-slot.
#define MFMA_SUB(J)                                                             \
    do {                                                                        \
        const int kh_ = (J) / 3, snib_ = ((J) % 3) * 3;                         \
        const unsigned char* bb_ = smem + ((J) % 4) * 12288 + (lane << 4);      \
        _Pragma("unroll")                                                       \
        for (int s_ = 0; s_ < 4; ++s_) {                                        \
            const bf16x8 a0_ = afr[(kh_ << 2) + s_];                            \
            const bf16x8 a1_ = afr[8 + (kh_ << 2) + s_];                        \
            _Pragma("unroll")                                                   \
            for (int ni_ = 0; ni_ < 3; ++ni_) {                                 \
                const bf16x8 bq_ = *(const bf16x8*)(bb_ + ((s_ * 3 + ni_) << 10)); \
                acc[0][snib_ + ni_] = __builtin_amdgcn_mfma_f32_16x16x32_bf16(  \
                    bq_, a0_, acc[0][snib_ + ni_], 0, 0, 0);                    \
                acc[1][snib_ + ni_] = __builtin_amdgcn_mfma_f32_16x16x32_bf16(  \
                    bq_, a1_, acc[1][snib_ + ni_], 0, 0, 0);                    \
            }                                                                   \
        }                                                                       \
    } while (0)

__global__ __launch_bounds__(512, 2) void dfgemm_kernel(
        const unsigned char* __restrict__ Wb, const float* __restrict__ x,
        const float* __restrict__ bias, float* __restrict__ out) {
    __shared__ __align__(16) unsigned char smem[49152];

    const int t = threadIdx.x;
    const int lane = t & 63, wv = t >> 6;        // wv 0..7
    const int quad = lane >> 4, lrow = lane & 15;

    const int b = blockIdx.x >> 6;               // image 0..3
    const int hp = blockIdx.x & 63;              // row pair
    const int h = (hp << 1) + (wv >> 2);         // this wave's row
    const int wq = wv & 3;                       // px quarter within the row

    // Warm the pipeline: chunk 0 subs 0..3 in flight while afr loads run.
    STAGE(0, 0); STAGE(0, 1); STAGE(0, 2); STAGE(0, 3);

    // ---- A fragments direct from x: afr[mi*8+gg][e] = bf16(x[b, gg*32+quad*8+e, h, w]) ----
    bf16x8 afr[16];
    {
        const float* xrow = x + ((size_t)b << 22) + (h << 7);
        #pragma unroll
        for (int mi = 0; mi < 2; ++mi) {
            const int w = (wq << 5) + (mi << 4) + lrow;
            #pragma unroll
            for (int gg = 0; gg < 8; ++gg) {
                const float* p = xrow + ((size_t)((gg << 5) + (quad << 3)) << 14) + w;
                float v[8];
                #pragma unroll
                for (int e = 0; e < 8; ++e) v[e] = p[(size_t)e << 14];
                uint4 pk;
                pk.x = pack2(v[0], v[1]); pk.y = pack2(v[2], v[3]);
                pk.z = pack2(v[4], v[5]); pk.w = pack2(v[6], v[7]);
                afr[(mi << 3) + gg] = *(const bf16x8*)&pk;
            }
        }
    }
    SYNC_VM(0);                        // prologue only: subs 0-3 landed, full drain

    #pragma unroll 1
    for (int chunk = 0; chunk < 16; ++chunk) {
        const int c1 = (chunk + 1) & 15;         // tail wraps: harmless re-stage
        f32x4 acc[2][9];
        const f32x4 zero = {0.f, 0.f, 0.f, 0.f};
        #pragma unroll
        for (int mi = 0; mi < 2; ++mi)
            #pragma unroll
            for (int ni = 0; ni < 9; ++ni) acc[mi][ni] = zero;

        // ph0: sub0 (staged ph5 prev) force-retired by the epilogue's
        // consumed bias/patch loads; VM(8) only bounds the <=8 out-stores.
        SYNC_VM(8);
        MFMA_SUB(0);

        SYNC_VM(8);                            // ph1: sub1 (pre-epi, FENCEd) retired
        STAGE(chunk, 4);                       // buf0 (sub0 readers drained)
        MFMA_SUB(1);

        SYNC_VM(8);                            // ph2: sub2 (ph3 prev) retired
        STAGE(chunk, 5);                       // buf1
        MFMA_SUB(2);

        SYNC_VM(8);                            // ph3: sub3 (ph4 prev) retired
        STAGE(c1, 2);                          // buf2
        MFMA_SUB(3);

        SYNC_VM(4);                            // ph4: retire sub4 (ph1); keep ph2+ph3
        STAGE(c1, 3);                          // buf3
        MFMA_SUB(4);

        SYNC_VM(4);                            // ph5: retire sub5 (ph2); keep ph3+ph4
        STAGE(c1, 0);                          // buf0 (sub4 readers drained)
        MFMA_SUB(5);

        SYNC_LG;                               // all M5 buf1 reads drained
        STAGE(c1, 1);                          // buf1; lands during epilogue
        FENCE;                                 // pin stage BEFORE patch loads/stores

        // ---- epilogue: pure-register. Lane owns pixel px=mi*16+lrow and 4
        //      whole channels (quad*4+c4); acc slot for (c4,p) is compile-time:
        //      idx=c4*9+p, ni=idx/4, j=idx%4. No LDS, no barriers. ----
        #pragma unroll
        for (int mi = 0; mi < 2; ++mi) {
            const int w = (wq << 5) + (mi << 4) + lrow;      // this lane's pixel
            #pragma unroll
            for (int c4 = 0; c4 < 4; ++c4) {
                const int cg = (chunk << 4) + (quad << 2) + c4;  // channel
                const float* bp = bias + cg * 9;
                const float* xc = x + ((size_t)((b << 8) + cg) << 14);
                float sum = 0.f;
                #pragma unroll
                for (int p = 0; p < 9; ++p) {
                    const int idx = c4 * 9 + p;
                    const int ni = idx >> 2, j = idx & 3;
                    const float yv = acc[mi][ni][j];
                    const int hh = h + p / 3 - 1, ww = w + p % 3 - 1;
                    float xv = 0.f;
                    if ((unsigned)hh < 128u && (unsigned)ww < 128u)
                        xv = xc[(hh << 7) + ww];             // fp32 patch
                    sum += (yv + bp[p]) * xv;
                }
                out[((size_t)((b << 8) + cg) << 14) + (h << 7) + w] = sum;
            }
        }
    }
}

extern "C" void kernel_launch(void* const* d_in, const int* in_sizes, int n_in,
                              void* d_out, int out_size, void* d_ws, size_t ws_size,
                              hipStream_t stream) {
    const float* x    = (const float*)d_in[0];   // 4*256*128*128
    const float* W    = (const float*)d_in[1];   // 2304*256
    const float* bias = (const float*)d_in[2];   // 2304
    float* out = (float*)d_out;

    unsigned char* Wb = (unsigned char*)d_ws;    // 1,179,648 B

    wconv_kernel<<<288, 256, 0, stream>>>(W, Wb);
    dfgemm_kernel<<<256, 512, 0, stream>>>(Wb, x, bias, out);
}

// Round 10
// 206.111 us; speedup vs baseline: 1.0931x; 1.0375x over previous
//
#include <hip/hip_runtime.h>

// DynamicFilter: out[b,c,h,w] = sum_p (y[c*9+p] + bias[c*9+p]) * x[b,c,h+dh,w+dw]
//   y[o] = sum_c' x[b,c',h,w] * W[o,c']   (GEMM M=65536, N=2304, K=256, bf16 MFMA)
// B=4, C=256, H=W=128, 9 taps.
// R11 (137us dfgemm): operand-swapped MFMA + channel-aligned Wb permutation
//   -> register-only epilogue, bank conflicts 0, VGPR 108. Still flat-low on
//   all pipes: grid 256 = 1 block/CU -> 8 waves/CU (25%) is the cap; every
//   stall covered by only 2 waves/SIMD. That cap explains R6/R9/R10/R11
//   flatness.
// R12: halve the per-wave M-tile to double residency. 1 row/block (grid 512),
//   wave = 16 px: afr 16->8 frags (32 VGPR), acc 18->9 f32x4 (36), need ~110
//   regs <= 128 cap -> __launch_bounds__(512,4) = 2 blocks/CU = 16 waves/CU
//   = 4 waves/SIMD (2x latency hiding). LDS 2x49152 = 98304 <= 160K. Wb
//   staging doubles chip-wide (~604 MB via L2 ~ 6 TB/s, far under ceiling).
//   Sync skeleton / STAGE / vmcnt counts byte-identical to R11 (stage +2
//   vm/wave; epilogue <=4 stores outstanding at loop top, SYNC_VM(8) safe).
//   (Unlike R7's spill: cap 128 vs need ~110, not cap 170 vs need ~184.)

typedef __attribute__((ext_vector_type(8))) short bf16x8;   // 8 bf16 = 4 VGPRs
typedef __attribute__((ext_vector_type(4))) float f32x4;    // MFMA 16x16 acc

__device__ __forceinline__ unsigned int f2bf(float f) {
    unsigned int u = __float_as_uint(f);
    return (u + 0x7fffu + ((u >> 16) & 1u)) >> 16;   // RNE
}
__device__ __forceinline__ unsigned int pack2(float a, float b) {
    return f2bf(a) | (f2bf(b) << 16);
}

// ---------------------------------------------------------------------------
// Kernel 1: W (2304x256 fp32) -> Wb bf16, instruction-ordered A-fragments
// with channel-aligned out permutation (unchanged from R11):
//   o: chunk=o/144, oc=o%144, c_local=oc/9, p=oc%9
//   q=c_local/4, c4=c_local%4, idx=c4*9+p, ni=idx/4, j=idx%4, r=q*4+j
//   k: kh=k/128, s=(k%128)/32, kq=(k%32)/8, e=k%8; jsub=kh*3+ni/3; ni_=ni%3
//   dst = chunk*73728 + jsub*12288 + (s*3+ni_)*1024 + (kq*16+r)*16 + e*2
// ---------------------------------------------------------------------------
__global__ __launch_bounds__(256) void wconv_kernel(const float* __restrict__ W,
                                                    unsigned char* __restrict__ Wb) {
    int idx0 = blockIdx.x * 256 + threadIdx.x;   // 73728 = 2304 * 32 groups
    int o = idx0 >> 5, g = idx0 & 31;
    const float4* src = (const float4*)(W + ((size_t)o << 8) + ((size_t)g << 3));
    float4 v0 = src[0], v1 = src[1];
    uint4 pk;
    pk.x = pack2(v0.x, v0.y); pk.y = pack2(v0.z, v0.w);
    pk.z = pack2(v1.x, v1.y); pk.w = pack2(v1.z, v1.w);
    int kh = g >> 4, g2 = g & 15, s = g2 >> 2, kq = g2 & 3;
    int chunk = o / 144, oc = o - chunk * 144;
    int c_local = oc / 9, p = oc - c_local * 9;
    int q = c_local >> 2, c4 = c_local & 3;
    int idx = c4 * 9 + p;
    int ni = idx >> 2, j = idx & 3, r = (q << 2) + j;
    int jsub = kh * 3 + ni / 3, ni_ = ni % 3;
    size_t dst = (size_t)chunk * 73728 + (size_t)jsub * 12288
               + (size_t)(s * 3 + ni_) * 1024 + (size_t)((kq << 4) + r) * 16;
    *(uint4*)(Wb + dst) = pk;
}

// ---------------------------------------------------------------------------
// Kernel 2. LDS map: ring bufs 0..3 at 0/12288/24576/36864 only. 49152 B.
// Sub-tile j (0..5): kh = j/3, ni-block = j%3, ring buf = j%4.
// Phase/WAR structure identical to R9..R11 (see R9 header chains).
// ---------------------------------------------------------------------------

#define SYNC_VM(N) asm volatile("s_waitcnt vmcnt(" #N ") lgkmcnt(0)\n\ts_barrier" ::: "memory")
#define SYNC_LG    asm volatile("s_waitcnt lgkmcnt(0)\n\ts_barrier" ::: "memory")
#define FENCE      asm volatile("" ::: "memory")   // compile-time order pin only

// Stage sub-tile J of chunk CH into ring buf J%4. Slices of 2048 B; wave wv
// stages slice wv%6 with 2 x global_load_lds(16B); waves 6,7 duplicate
// slices 0,1 (identical bytes). Per-wave vmcnt += 2, uniform across waves.
#define STAGE(CH, J)                                                            \
    do {                                                                        \
        const int sl_ = (wv < 6) ? wv : (wv - 6);                               \
        const unsigned char* bs_ = Wb + (size_t)(CH) * 73728                    \
            + (size_t)(J) * 12288 + sl_ * 2048 + (lane << 4);                   \
        unsigned char* bd_ = smem + ((J) % 4) * 12288 + sl_ * 2048;             \
        __builtin_amdgcn_global_load_lds(                                       \
            (const __attribute__((address_space(1))) void*)(bs_),               \
            (__attribute__((address_space(3))) void*)(bd_), 16, 0, 0);          \
        __builtin_amdgcn_global_load_lds(                                       \
            (const __attribute__((address_space(1))) void*)(bs_ + 1024),        \
            (__attribute__((address_space(3))) void*)(bd_ + 1024), 16, 0, 0);   \
    } while (0)

// 12 MFMAs on sub-tile J (3 ni x 4 s, single 16-px M-tile). A = Wb fragment
// (uniform base + lane*16, conflict-free), B = afr (pixel operand).
// acc[ni] = C[out_row][px_col]: col=lane&15=px, row=quad*4+reg=out-slot.
#define MFMA_SUB(J)                                                             \
    do {                                                                        \
        const int kh_ = (J) / 3, snib_ = ((J) % 3) * 3;                         \
        const unsigned char* bb_ = smem + ((J) % 4) * 12288 + (lane << 4);      \
        _Pragma("unroll")                                                       \
        for (int s_ = 0; s_ < 4; ++s_) {                                        \
            const bf16x8 a_ = afr[(kh_ << 2) + s_];                             \
            _Pragma("unroll")                                                   \
            for (int ni_ = 0; ni_ < 3; ++ni_) {                                 \
                const bf16x8 bq_ = *(const bf16x8*)(bb_ + ((s_ * 3 + ni_) << 10)); \
                acc[snib_ + ni_] = __builtin_amdgcn_mfma_f32_16x16x32_bf16(     \
                    bq_, a_, acc[snib_ + ni_], 0, 0, 0);                        \
            }                                                                   \
        }                                                                       \
    } while (0)

__global__ __launch_bounds__(512, 4) void dfgemm_kernel(
        const unsigned char* __restrict__ Wb, const float* __restrict__ x,
        const float* __restrict__ bias, float* __restrict__ out) {
    __shared__ __align__(16) unsigned char smem[49152];

    const int t = threadIdx.x;
    const int lane = t & 63, wv = t >> 6;        // wv 0..7
    const int quad = lane >> 4, lrow = lane & 15;

    const int b = blockIdx.x >> 7;               // image 0..3
    const int h = blockIdx.x & 127;              // row
    const int w = (wv << 4) + lrow;              // this lane's pixel (16/wave)

    // Warm the pipeline: chunk 0 subs 0..3 in flight while afr loads run.
    STAGE(0, 0); STAGE(0, 1); STAGE(0, 2); STAGE(0, 3);

    // ---- A(pixel) fragments direct from x: afr[gg][e] = bf16(x[b, gg*32+quad*8+e, h, w]) ----
    bf16x8 afr[8];
    {
        const float* xrow = x + ((size_t)b << 22) + (h << 7);
        #pragma unroll
        for (int gg = 0; gg < 8; ++gg) {
            const float* p = xrow + ((size_t)((gg << 5) + (quad << 3)) << 14) + w;
            float v[8];
            #pragma unroll
            for (int e = 0; e < 8; ++e) v[e] = p[(size_t)e << 14];
            uint4 pk;
            pk.x = pack2(v[0], v[1]); pk.y = pack2(v[2], v[3]);
            pk.z = pack2(v[4], v[5]); pk.w = pack2(v[6], v[7]);
            afr[gg] = *(const bf16x8*)&pk;
        }
    }
    SYNC_VM(0);                        // prologue only: subs 0-3 landed, full drain

    #pragma unroll 1
    for (int chunk = 0; chunk < 16; ++chunk) {
        const int c1 = (chunk + 1) & 15;         // tail wraps: harmless re-stage
        f32x4 acc[9];
        const f32x4 zero = {0.f, 0.f, 0.f, 0.f};
        #pragma unroll
        for (int ni = 0; ni < 9; ++ni) acc[ni] = zero;

        // ph0: sub0 (staged ph5 prev) force-retired by the epilogue's
        // consumed bias/patch loads; VM(8) only bounds the <=4 out-stores.
        SYNC_VM(8);
        MFMA_SUB(0);

        SYNC_VM(8);                            // ph1: sub1 (pre-epi, FENCEd) retired
        STAGE(chunk, 4);                       // buf0 (sub0 readers drained)
        MFMA_SUB(1);

        SYNC_VM(8);                            // ph2: sub2 (ph3 prev) retired
        STAGE(chunk, 5);                       // buf1
        MFMA_SUB(2);

        SYNC_VM(8);                            // ph3: sub3 (ph4 prev) retired
        STAGE(c1, 2);                          // buf2
        MFMA_SUB(3);

        SYNC_VM(4);                            // ph4: retire sub4 (ph1); keep ph2+ph3
        STAGE(c1, 3);                          // buf3
        MFMA_SUB(4);

        SYNC_VM(4);                            // ph5: retire sub5 (ph2); keep ph3+ph4
        STAGE(c1, 0);                          // buf0 (sub4 readers drained)
        MFMA_SUB(5);

        SYNC_LG;                               // all M5 buf1 reads drained
        STAGE(c1, 1);                          // buf1; lands during epilogue
        FENCE;                                 // pin stage BEFORE patch loads/stores

        // ---- epilogue: pure-register. Lane owns pixel w and 4 whole
        //      channels (quad*4+c4); acc slot for (c4,p) is compile-time:
        //      idx=c4*9+p, ni=idx/4, j=idx%4. No LDS, no barriers. ----
        #pragma unroll
        for (int c4 = 0; c4 < 4; ++c4) {
            const int cg = (chunk << 4) + (quad << 2) + c4;  // channel
            const float* bp = bias + cg * 9;
            const float* xc = x + ((size_t)((b << 8) + cg) << 14);
            float sum = 0.f;
            #pragma unroll
            for (int p = 0; p < 9; ++p) {
                const int idx = c4 * 9 + p;
                const int ni = idx >> 2, j = idx & 3;
                const float yv = acc[ni][j];
                const int hh = h + p / 3 - 1, ww = w + p % 3 - 1;
                float xv = 0.f;
                if ((unsigned)hh < 128u && (unsigned)ww < 128u)
                    xv = xc[(hh << 7) + ww];                 // fp32 patch
                sum += (yv + bp[p]) * xv;
            }
            out[((size_t)((b << 8) + cg) << 14) + (h << 7) + w] = sum;
        }
    }
}

extern "C" void kernel_launch(void* const* d_in, const int* in_sizes, int n_in,
                              void* d_out, int out_size, void* d_ws, size_t ws_size,
                              hipStream_t stream) {
    const float* x    = (const float*)d_in[0];   // 4*256*128*128
    const float* W    = (const float*)d_in[1];   // 2304*256
    const float* bias = (const float*)d_in[2];   // 2304
    float* out = (float*)d_out;

    unsigned char* Wb = (unsigned char*)d_ws;    // 1,179,648 B

    wconv_kernel<<<288, 256, 0, stream>>>(W, Wb);
    dfgemm_kernel<<<512, 512, 0, stream>>>(Wb, x, bias, out);
}